// Round 9
// baseline (235.998 us; speedup 1.0000x reference)
//
#include <hip/hip_runtime.h>
#include <math.h>

// B=64, S=256, D=1024, T=60, HIST=20. All tensors fp32.
// R14: occupancy + launch-merge.
//  - qw_gemm: 128x128 (240 blocks = 1/CU, no TLP) -> 64x128 (480 blocks,
//    ~2/CU, 48KB LDS -> 3/CU by LDS). Same dbuf gload_lds w16 + involution.
//  - scan fused into gemm_g via last-block-done: 8 s-tile blocks per b
//    atomicAdd a counter (zeroed by qw_gemm, prior launch); the last runs the
//    R12 register-resident scan for its b. Saves a launch + gap.
//  - convAll, gemm_sels unchanged.

#define Bn 64
#define Sn 256
#define Dn 1024
#define Tn 60
#define HISTn 20
#define LDK 72
#define K05 1.0512710963760241f   // e^{0.05}
#define EINV 0.36787944117144233f // e^{-1}
#define LOG2E 1.4426950408889634f

typedef __bf16 bf16x8 __attribute__((ext_vector_type(8)));
typedef float f32x4 __attribute__((ext_vector_type(4)));
typedef unsigned short us8 __attribute__((ext_vector_type(8)));

typedef const __attribute__((address_space(1))) unsigned int* gas_u32p;
typedef __attribute__((address_space(3))) unsigned int* las_u32p;

__device__ __forceinline__ void gl16(const unsigned short* g, unsigned short* l){
  __builtin_amdgcn_global_load_lds((gas_u32p)g, (las_u32p)l, 16, 0, 0);
}

__device__ __forceinline__ unsigned short f2bf(float f){
  unsigned int x; __builtin_memcpy(&x,&f,4);
  unsigned int lsb = (x >> 16) & 1u;
  x += 0x7fffu + lsb;
  return (unsigned short)(x >> 16);
}
// fast sigmoid: 1/(1+2^(-x*log2e)) -- v_exp_f32 + v_rcp_f32
__device__ __forceinline__ float sigmoidf_(float x){
  float e = __builtin_amdgcn_exp2f(-x * LOG2E);
  return __builtin_amdgcn_rcpf(1.0f + e);
}

// ------ convAll: [0,3840) Q; [3840,4096) Wq^T; [4096,8192) E ---------------
__global__ __launch_bounds__(256) void convAll(
    const float* __restrict__ Q, const float* __restrict__ Wr,
    const float* __restrict__ br, const float* __restrict__ Wa,
    const float* __restrict__ ba, const float* __restrict__ Wq,
    const float* __restrict__ E, const float* __restrict__ Wn,
    float* __restrict__ rp, float* __restrict__ ap,
    unsigned short* __restrict__ Qbf, unsigned short* __restrict__ WT,
    unsigned short* __restrict__ Ebf,
    float* __restrict__ eW1, float* __restrict__ eW2)
{
  int tid = threadIdx.x;
  int bx = blockIdx.x;
  if (bx < Bn*Tn){
    int row = bx;
    float4 x = ((const float4*)(Q + (size_t)row*Dn))[tid];
    float4 a = ((const float4*)Wr)[tid];
    float4 b = ((const float4*)Wa)[tid];
    unsigned short o[4] = {f2bf(x.x), f2bf(x.y), f2bf(x.z), f2bf(x.w)};
    *(uint2*)&Qbf[(size_t)row*Dn + tid*4] = *(uint2*)o;
    float s1 = x.x*a.x + x.y*a.y + x.z*a.z + x.w*a.w;
    float s2 = x.x*b.x + x.y*b.y + x.z*b.z + x.w*b.w;
    for (int off = 32; off; off >>= 1){
      s1 += __shfl_down(s1, off, 64);
      s2 += __shfl_down(s2, off, 64);
    }
    __shared__ float r1[4], r2[4];
    int lane = tid & 63, wv = tid >> 6;
    if (lane == 0){ r1[wv] = s1; r2[wv] = s2; }
    __syncthreads();
    if (tid == 0){
      rp[row] = sigmoidf_(r1[0]+r1[1]+r1[2]+r1[3] + br[0]);
      ap[row] = sigmoidf_(r2[0]+r2[1]+r2[2]+r2[3] + ba[0]);
    }
  } else if (bx < Bn*Tn + 256){
    __shared__ __align__(16) unsigned short Tt[64][LDK];
    int t = bx - Bn*Tn;
    int n0 = (t >> 4)*64, k0 = (t & 15)*64;
    int kl = tid >> 4, nl4 = (tid & 15)*4;
    #pragma unroll
    for (int it = 0; it < 4; it++){
      int k = kl + it*16;
      float4 v = *(const float4*)&Wq[(size_t)(k0+k)*Dn + n0 + nl4];
      Tt[nl4+0][k] = f2bf(v.x); Tt[nl4+1][k] = f2bf(v.y);
      Tt[nl4+2][k] = f2bf(v.z); Tt[nl4+3][k] = f2bf(v.w);
    }
    __syncthreads();
    int nr = tid >> 2, kg = (tid & 3)*16;
    *(us8*)&WT[(size_t)(n0+nr)*Dn + k0+kg]   = *(us8*)&Tt[nr][kg];
    *(us8*)&WT[(size_t)(n0+nr)*Dn + k0+kg+8] = *(us8*)&Tt[nr][kg+8];
  } else {
    // E part: 4 rows per block, one row per 64-lane wave
    int row = (bx - (Bn*Tn + 256))*4 + (tid >> 6);
    int lane = tid & 63;
    const float* er = E + (size_t)row*Dn;
    unsigned short* ebr = Ebf + (size_t)row*Dn;
    float d1 = 0.f, d2 = 0.f;
    #pragma unroll
    for (int c = 0; c < 4; c++){
      int idx = c*64 + lane;
      float4 v = ((const float4*)er)[idx];
      float4 w1 = ((const float4*)Wn)[idx];
      float4 w2 = ((const float4*)(Wn + Dn))[idx];
      unsigned short o[4] = {f2bf(v.x), f2bf(v.y), f2bf(v.z), f2bf(v.w)};
      ((uint2*)ebr)[idx] = *(uint2*)o;
      d1 += v.x*w1.x + v.y*w1.y + v.z*w1.z + v.w*w1.w;
      d2 += v.x*w2.x + v.y*w2.y + v.z*w2.z + v.w*w2.w;
    }
    #pragma unroll
    for (int off = 32; off; off >>= 1){
      d1 += __shfl_down(d1, off, 64);
      d2 += __shfl_down(d2, off, 64);
    }
    if (lane == 0){ eW1[row] = d1; eW2[row] = d2; }
  }
}

// ------ qw_gemm: QW = Q @ Wq, 64x128 tiles, 480 blocks (~2/CU) -------------
__global__ __launch_bounds__(256) void qw_gemm(
    const unsigned short* __restrict__ Qbf,
    const unsigned short* __restrict__ WT,
    unsigned short* __restrict__ QWbf,
    unsigned int* __restrict__ cnt)
{
  int tid = threadIdx.x;
  if (tid == 0 && blockIdx.x < Bn) cnt[blockIdx.x] = 0;  // flags for gemm_g tail
  // LDS: A 64x64 (8KB) + B 128x64 (16KB), double-buffered = 48KB.
  __shared__ __align__(16) unsigned short As0_[64*64],  Bs0_[128*64];
  __shared__ __align__(16) unsigned short As1_[64*64],  Bs1_[128*64];
  // 480 blocks = 60 m-tiles(64) x 8 n-tiles(128); XCD swizzle chunk=60.
  int bx = (blockIdx.x & 7)*60 + (blockIdx.x >> 3);
  int m0 = (bx >> 3)*64, n0 = (bx & 7)*128;
  int lane = tid & 63, wave = tid >> 6;
  int quad = lane >> 4, l16 = lane & 15;
  int wr = (wave >> 1)*32, wc = (wave & 1)*64;   // wave covers 32m x 64n
  f32x4 acc[2][4];
  #pragma unroll
  for (int mi=0;mi<2;mi++)
    #pragma unroll
    for (int ni=0;ni<4;ni++)
      #pragma unroll
      for (int r=0;r<4;r++) acc[mi][ni][r]=0.f;
  int lr = lane >> 3;                          // row within 8-row chunk
  int scol = ((lane & 7) ^ lr)*8;              // pre-swizzled source col
  const unsigned short* gA = Qbf + (size_t)(m0 + lr)*Dn + scol;
  const unsigned short* gB = WT  + (size_t)(n0 + lr)*Dn + scol;

  #define STAGE64(K, A_, B_) { \
    _Pragma("unroll") \
    for (int i = 0; i < 2; i++){ \
      int c = wave*2 + i; \
      gl16(gA + (size_t)c*8*Dn + (K), &A_[c*512]); \
    } \
    _Pragma("unroll") \
    for (int i = 0; i < 4; i++){ \
      int c = wave*4 + i; \
      gl16(gB + (size_t)c*8*Dn + (K), &B_[c*512]); \
    } }
  #define COMP64(A_, B_) { \
    _Pragma("unroll") \
    for (int ks = 0; ks < 2; ks++){ \
      bf16x8 af[2], bg[4]; \
      _Pragma("unroll") \
      for (int mi=0;mi<2;mi++){ \
        int mrow = wr + mi*16 + l16; \
        af[mi] = *(const bf16x8*)&A_[mrow*64 + ((ks*32 + quad*8) ^ ((mrow&7)*8))]; \
      } \
      _Pragma("unroll") \
      for (int ni=0;ni<4;ni++){ \
        int nrow = wc + ni*16 + l16; \
        bg[ni] = *(const bf16x8*)&B_[nrow*64 + ((ks*32 + quad*8) ^ ((nrow&7)*8))]; \
      } \
      _Pragma("unroll") \
      for (int mi=0;mi<2;mi++) \
        _Pragma("unroll") \
        for (int ni=0;ni<4;ni++) \
          acc[mi][ni] = __builtin_amdgcn_mfma_f32_16x16x32_bf16(af[mi], bg[ni], acc[mi][ni], 0, 0, 0); \
    } }

  STAGE64(0, As0_, Bs0_);
  __syncthreads();
  #pragma unroll 1
  for (int k0 = 0; k0 < Dn; k0 += 128){
    STAGE64(k0+64, As1_, Bs1_);        // k0+64 <= 960 < Dn always
    COMP64(As0_, Bs0_);
    __syncthreads();
    if (k0+128 < Dn) STAGE64(k0+128, As0_, Bs0_);
    COMP64(As1_, Bs1_);
    __syncthreads();
  }
  #undef STAGE64
  #undef COMP64

  #pragma unroll
  for (int mi=0;mi<2;mi++)
    #pragma unroll
    for (int ni=0;ni<4;ni++)
      #pragma unroll
      for (int r=0;r<4;r++){
        int m = m0 + wr + mi*16 + quad*4 + r;
        int n = n0 + wc + ni*16 + l16;
        QWbf[(size_t)m*Dn + n] = f2bf(acc[mi][ni][r]);
      }
}

// ------ gemm_g: 60x32 G-tiles; LAST of each b's 8 blocks runs the scan ------
__global__ __launch_bounds__(256) void gemm_g(
    const unsigned short* __restrict__ QWbf,
    const unsigned short* __restrict__ Ebf,
    const float* __restrict__ At,
    const float* __restrict__ rp,
    const float* __restrict__ ap,
    const float* __restrict__ eW1,
    const float* __restrict__ eW2,
    const float* __restrict__ bnp,
    float* __restrict__ G,
    unsigned short* __restrict__ Pbf,
    unsigned int* __restrict__ cnt)
{
  __shared__ __align__(16) unsigned short As0_[64][LDK], As1_[64][LDK];
  __shared__ __align__(16) unsigned short Bs0_[32][LDK], Bs1_[32][LDK];
  int b = blockIdx.x, s0 = blockIdx.y*32;
  int tid = threadIdx.x, lane = tid & 63, wave = tid >> 6;
  int quad = lane >> 4, l16 = lane & 15;
  f32x4 acc[2];
  #pragma unroll
  for (int nt=0;nt<2;nt++)
    #pragma unroll
    for (int r=0;r<4;r++) acc[nt][r]=0.f;
  int sr = tid >> 2, sk = (tid & 3)*16;   // A staging: 64 rows x 64 k
  int brw = tid >> 3, bk = (tid & 7)*8;   // B staging: 32 rows x 64 k
  const unsigned short* aRow = QWbf + ((size_t)(b*Tn + sr))*Dn;
  const unsigned short* bRow = Ebf  + ((size_t)(b*Sn + s0 + brw))*Dn;

  #define LOADR(K, ra0, ra1, rb0) { \
    if (sr < Tn){ ra0 = *(const us8*)&aRow[(K)+sk]; ra1 = *(const us8*)&aRow[(K)+sk+8]; } \
    else { ra0 = (us8)0; ra1 = (us8)0; } \
    rb0 = *(const us8*)&bRow[(K)+bk]; }
  #define STORER(A_, B_, ra0, ra1, rb0) { \
    *(us8*)&A_[sr][sk]   = ra0; *(us8*)&A_[sr][sk+8] = ra1; \
    *(us8*)&B_[brw][bk]  = rb0; }
  #define COMP_G(A_, B_) { \
    _Pragma("unroll") \
    for (int kk = 0; kk < 64; kk += 32){ \
      bf16x8 a = *(const bf16x8*)&A_[wave*16 + l16][kk + quad*8]; \
      _Pragma("unroll") \
      for (int nt=0;nt<2;nt++){ \
        bf16x8 bb = *(const bf16x8*)&B_[nt*16 + l16][kk + quad*8]; \
        acc[nt] = __builtin_amdgcn_mfma_f32_16x16x32_bf16(a, bb, acc[nt], 0, 0, 0); \
      } \
    } }

  us8 pa0, pa1, pb0, qa0, qa1, qb0;
  LOADR(0, pa0, pa1, pb0);
  STORER(As0_, Bs0_, pa0, pa1, pb0);
  #pragma unroll 1
  for (int k0 = 0; k0 < Dn; k0 += 128){
    LOADR(k0+64, qa0, qa1, qb0);          // k0+64 <= 960 < Dn always
    __syncthreads();
    COMP_G(As0_, Bs0_);
    STORER(As1_, Bs1_, qa0, qa1, qb0);
    if (k0+128 < Dn) LOADR(k0+128, pa0, pa1, pb0);
    __syncthreads();
    COMP_G(As1_, Bs1_);
    if (k0+128 < Dn) STORER(As0_, Bs0_, pa0, pa1, pb0);
  }
  #undef LOADR
  #undef STORER
  #undef COMP_G

  #pragma unroll
  for (int nt=0;nt<2;nt++)
    #pragma unroll
    for (int r=0;r<4;r++){
      int t = wave*16 + quad*4 + r;
      if (t < Tn) G[((size_t)(b*Tn + t))*Sn + s0 + nt*16 + l16] = acc[nt][r];
    }

  // ---- last-block-done: 8th finisher of this b runs the scan ----
  __threadfence();                         // release G writes (device scope)
  __shared__ unsigned int lastFlag;
  if (tid == 0){
    unsigned int v = atomicAdd(&cnt[b], 1u);
    lastFlag = (v == 7u);
  }
  __syncthreads();
  if (!lastFlag) return;
  __threadfence();                         // acquire: siblings' G visible

  __shared__ float Rsh[Tn], lcs[Tn], rps[Tn], aps[Tn], invd[Tn];
  // 1) Burst-load this thread's At/G column into registers (static idx only).
  float a_[Tn], g_[Tn];
  {
    const float* at_c = At + (size_t)b*Tn*Sn + tid;
    const float* g_c  = G  + (size_t)b*Tn*Sn + tid;
    #pragma unroll
    for (int i = 0; i < Tn; i++){
      a_[i] = at_c[(size_t)i*Sn];
      g_[i] = g_c[(size_t)i*Sn];
    }
  }
  // 2) R-dot: R[j] = At[b,j,:].eW2[b,:]
  {
    float4 e2v = ((const float4*)(eW2 + (size_t)b*Sn))[lane];
    const float* at_b = At + (size_t)b*Tn*Sn;
    #pragma unroll
    for (int w = 0; w < 15; w++){
      int j = wave + w*4;
      float4 a4 = ((const float4*)(at_b + (size_t)j*Sn))[lane];
      float v = a4.x*e2v.x + a4.y*e2v.y + a4.z*e2v.z + a4.w*e2v.w;
      #pragma unroll
      for (int off = 32; off; off >>= 1) v += __shfl_down(v, off, 64);
      if (lane == 0) Rsh[j] = v;
    }
  }
  if (tid < Tn){
    rps[tid] = rp[b*Tn + tid];
    aps[tid] = ap[b*Tn + tid];
  }
  __syncthreads();
  // 3) lc + 1/den
  if (tid < Tn){
    int i = tid;
    int j0 = (i - HISTn + 1 > 0) ? i - HISTn + 1 : 0;
    float num = 0.f, den = 0.f, wj = 1.f;
    #pragma unroll 1
    for (int j = 0; j <= i; j++){
      wj *= K05;
      if (j >= j0){ num += wj * Rsh[j]; den += wj; }
    }
    float inv = __builtin_amdgcn_rcpf(den);
    lcs[i] = num * inv;
    invd[i] = inv;
  }
  __syncthreads();
  // 4) 60-step recurrence, fully unrolled, pure-register.
  {
    int s = tid;
    float M = (s < 50) ? (1.0f - (s+1)/50.0f) : 0.0f;
    float A = M;
    float bnv = bnp[0];
    float e1 = eW1[b*Sn + s];
    unsigned short* P_b = Pbf + (size_t)b*Tn*Sn + s;
    float num_a = 0.f, num_q = 0.f, wi = 1.f;
    #pragma unroll
    for (int i = 0; i < Tn; i++){
      wi *= K05;
      num_a += wi * a_[i];
      num_q += wi * g_[i];
      if (i >= HISTn){
        float wo = wi * EINV;
        num_a -= wo * a_[i-HISTn];
        num_q -= wo * g_[i-HISTn];
      }
      float inv = invd[i];
      float aw = num_a * inv;
      float qd = num_q * inv;
      P_b[(size_t)i*Sn] = f2bf(a_[i] * M);   // sel uses mem at step ENTRY
      float sim = sigmoidf_(M * qd);
      float nxt = sigmoidf_(e1 + lcs[i] + bnv);
      M = M * (1.0f - rps[i] * aw * sim);
      float g = (1.0f - A) * aps[i] * nxt;
      M += g; A += g;
    }
  }
}

// ------ gemm_sels: out[b] = P[b](TxS) @ Ebf[b](SxD), single-buffer + T14 ----
__global__ __launch_bounds__(256) void gemm_sels(
    const unsigned short* __restrict__ Pbf,
    const unsigned short* __restrict__ Ebf,
    float* __restrict__ out)
{
  __shared__ __align__(16) unsigned short As_[64][LDK], Bs_[64][LDK];
  int b = blockIdx.x, n0 = blockIdx.y*64;   // n over D
  int tid = threadIdx.x, lane = tid & 63, wave = tid >> 6;
  int quad = lane >> 4, l16 = lane & 15;
  f32x4 acc[4];
  #pragma unroll
  for (int nt=0;nt<4;nt++)
    #pragma unroll
    for (int r=0;r<4;r++) acc[nt][r]=0.f;
  int sr = tid >> 2, sk = (tid & 3)*16;

  #define SLOAD(K) { \
    if (sr < Tn){ \
      const unsigned short* pp = &Pbf[((size_t)(b*Tn + sr))*Sn + (K)+sk]; \
      pa0 = *(const us8*)pp; pa1 = *(const us8*)(pp+8); \
    } else { pa0 = (us8)0; pa1 = (us8)0; } \
    const unsigned short* ep = &Ebf[((size_t)(b*Sn + (K) + sr))*Dn + n0 + sk]; \
    pe0 = *(const us8*)ep; pe1 = *(const us8*)(ep + 8); }
  #define SSTORE() { \
    *(us8*)&As_[sr][sk]   = pa0; *(us8*)&As_[sr][sk+8] = pa1; \
    _Pragma("unroll") \
    for (int j=0;j<8;j++){ \
      Bs_[sk+j][sr]   = pe0[j]; \
      Bs_[sk+8+j][sr] = pe1[j]; } }
  #define COMP_S() { \
    _Pragma("unroll") \
    for (int kk = 0; kk < 64; kk += 32){ \
      bf16x8 a = *(const bf16x8*)&As_[wave*16 + l16][kk + quad*8]; \
      _Pragma("unroll") \
      for (int nt=0;nt<4;nt++){ \
        bf16x8 bb = *(const bf16x8*)&Bs_[nt*16 + l16][kk + quad*8]; \
        acc[nt] = __builtin_amdgcn_mfma_f32_16x16x32_bf16(a, bb, acc[nt], 0, 0, 0); \
      } \
    } }

  us8 pa0, pa1, pe0, pe1;
  SLOAD(0);
  SSTORE();
  #pragma unroll
  for (int k0 = 0; k0 < Sn; k0 += 64){
    __syncthreads();                       // stores visible
    if (k0+64 < Sn) SLOAD(k0+64);          // issue next loads early (T14)
    COMP_S();
    __syncthreads();                       // reads done before overwrite
    if (k0+64 < Sn) SSTORE();
  }
  #undef SLOAD
  #undef SSTORE
  #undef COMP_S

  #pragma unroll
  for (int nt=0;nt<4;nt++)
    #pragma unroll
    for (int r=0;r<4;r++){
      int t = wave*16 + quad*4 + r;
      int d = n0 + nt*16 + l16;
      if (t < Tn) out[((size_t)(b*Tn + t))*Dn + d] = acc[nt][r];
    }
}

extern "C" void kernel_launch(void* const* d_in, const int* in_sizes, int n_in,
                              void* d_out, int out_size, void* d_ws, size_t ws_size,
                              hipStream_t stream)
{
  const float* E  = (const float*)d_in[0];
  const float* Q  = (const float*)d_in[1];
  const float* At = (const float*)d_in[2];
  const float* Wr = (const float*)d_in[3];
  const float* br = (const float*)d_in[4];
  const float* Wa = (const float*)d_in[5];
  const float* ba = (const float*)d_in[6];
  const float* Wq = (const float*)d_in[7];
  const float* Wn = (const float*)d_in[8];
  const float* bnp= (const float*)d_in[9];

  char* ws = (char*)d_ws;
  float* rp  = (float*)ws; ws += (size_t)Bn*Tn*4;
  float* ap  = (float*)ws; ws += (size_t)Bn*Tn*4;
  float* eW1 = (float*)ws; ws += (size_t)Bn*Sn*4;
  float* eW2 = (float*)ws; ws += (size_t)Bn*Sn*4;
  unsigned short* Qbf  = (unsigned short*)ws; ws += (size_t)Bn*Tn*Dn*2;  // 7.86 MB
  unsigned short* WT   = (unsigned short*)ws; ws += (size_t)Dn*Dn*2;     // 2.1 MB
  unsigned short* QWbf = (unsigned short*)ws; ws += (size_t)Bn*Tn*Dn*2;  // 7.86 MB
  unsigned short* Ebf  = (unsigned short*)ws; ws += (size_t)Bn*Sn*Dn*2;  // 33.6 MB
  float* G = (float*)ws; ws += (size_t)Bn*Tn*Sn*4;                       // 3.93 MB
  unsigned short* Pbf = (unsigned short*)ws; ws += (size_t)Bn*Tn*Sn*2;   // 1.97 MB
  unsigned int* cnt = (unsigned int*)ws; ws += (size_t)Bn*4;             // 256 B

  convAll<<<Bn*Tn + 256 + Bn*Sn/4, 256, 0, stream>>>(
      Q, Wr, br, Wa, ba, Wq, E, Wn, rp, ap, Qbf, WT, Ebf, eW1, eW2);
  qw_gemm<<<480, 256, 0, stream>>>(Qbf, WT, QWbf, cnt);
  gemm_g<<<dim3(Bn, Sn/32), 256, 0, stream>>>(
      QWbf, Ebf, At, rp, ap, eW1, eW2, bnp, G, Pbf, cnt);
  gemm_sels<<<dim3(Bn, Dn/64), 256, 0, stream>>>(Pbf, Ebf, (float*)d_out);
}

// Round 11
// 184.296 us; speedup vs baseline: 1.2805x; 1.2805x over previous
//
#include <hip/hip_runtime.h>
#include <math.h>

// B=64, S=256, D=1024, T=60, HIST=20. All tensors fp32.
// R15 (resubmit; R10 bench was a GPU-acquisition timeout, kernel never ran):
// revert R14's scan-fusion (gemm_g hit 81us: the 120-float register
// arrays spilled to scratch in the fused kernel -- VGPR=92 < 120 needed;
// standalone scan_s keeps them in VGPRs). Keep the one untested R14 change:
// qw_gemm at 64x128/480 blocks (~2/CU vs 240=1/CU, TLP covers barrier
// drains). convAll, gemm_g(32-wide), scan_s(register), gemm_sels = R13.

#define Bn 64
#define Sn 256
#define Dn 1024
#define Tn 60
#define HISTn 20
#define LDK 72
#define K05 1.0512710963760241f   // e^{0.05}
#define EINV 0.36787944117144233f // e^{-1}
#define LOG2E 1.4426950408889634f

typedef __bf16 bf16x8 __attribute__((ext_vector_type(8)));
typedef float f32x4 __attribute__((ext_vector_type(4)));
typedef unsigned short us8 __attribute__((ext_vector_type(8)));

typedef const __attribute__((address_space(1))) unsigned int* gas_u32p;
typedef __attribute__((address_space(3))) unsigned int* las_u32p;

__device__ __forceinline__ void gl16(const unsigned short* g, unsigned short* l){
  __builtin_amdgcn_global_load_lds((gas_u32p)g, (las_u32p)l, 16, 0, 0);
}

__device__ __forceinline__ unsigned short f2bf(float f){
  unsigned int x; __builtin_memcpy(&x,&f,4);
  unsigned int lsb = (x >> 16) & 1u;
  x += 0x7fffu + lsb;
  return (unsigned short)(x >> 16);
}
// fast sigmoid: 1/(1+2^(-x*log2e)) -- v_exp_f32 + v_rcp_f32
__device__ __forceinline__ float sigmoidf_(float x){
  float e = __builtin_amdgcn_exp2f(-x * LOG2E);
  return __builtin_amdgcn_rcpf(1.0f + e);
}

// ------ convAll: [0,3840) Q; [3840,4096) Wq^T; [4096,8192) E ---------------
__global__ __launch_bounds__(256) void convAll(
    const float* __restrict__ Q, const float* __restrict__ Wr,
    const float* __restrict__ br, const float* __restrict__ Wa,
    const float* __restrict__ ba, const float* __restrict__ Wq,
    const float* __restrict__ E, const float* __restrict__ Wn,
    float* __restrict__ rp, float* __restrict__ ap,
    unsigned short* __restrict__ Qbf, unsigned short* __restrict__ WT,
    unsigned short* __restrict__ Ebf,
    float* __restrict__ eW1, float* __restrict__ eW2)
{
  int tid = threadIdx.x;
  int bx = blockIdx.x;
  if (bx < Bn*Tn){
    int row = bx;
    float4 x = ((const float4*)(Q + (size_t)row*Dn))[tid];
    float4 a = ((const float4*)Wr)[tid];
    float4 b = ((const float4*)Wa)[tid];
    unsigned short o[4] = {f2bf(x.x), f2bf(x.y), f2bf(x.z), f2bf(x.w)};
    *(uint2*)&Qbf[(size_t)row*Dn + tid*4] = *(uint2*)o;
    float s1 = x.x*a.x + x.y*a.y + x.z*a.z + x.w*a.w;
    float s2 = x.x*b.x + x.y*b.y + x.z*b.z + x.w*b.w;
    for (int off = 32; off; off >>= 1){
      s1 += __shfl_down(s1, off, 64);
      s2 += __shfl_down(s2, off, 64);
    }
    __shared__ float r1[4], r2[4];
    int lane = tid & 63, wv = tid >> 6;
    if (lane == 0){ r1[wv] = s1; r2[wv] = s2; }
    __syncthreads();
    if (tid == 0){
      rp[row] = sigmoidf_(r1[0]+r1[1]+r1[2]+r1[3] + br[0]);
      ap[row] = sigmoidf_(r2[0]+r2[1]+r2[2]+r2[3] + ba[0]);
    }
  } else if (bx < Bn*Tn + 256){
    __shared__ __align__(16) unsigned short Tt[64][LDK];
    int t = bx - Bn*Tn;
    int n0 = (t >> 4)*64, k0 = (t & 15)*64;
    int kl = tid >> 4, nl4 = (tid & 15)*4;
    #pragma unroll
    for (int it = 0; it < 4; it++){
      int k = kl + it*16;
      float4 v = *(const float4*)&Wq[(size_t)(k0+k)*Dn + n0 + nl4];
      Tt[nl4+0][k] = f2bf(v.x); Tt[nl4+1][k] = f2bf(v.y);
      Tt[nl4+2][k] = f2bf(v.z); Tt[nl4+3][k] = f2bf(v.w);
    }
    __syncthreads();
    int nr = tid >> 2, kg = (tid & 3)*16;
    *(us8*)&WT[(size_t)(n0+nr)*Dn + k0+kg]   = *(us8*)&Tt[nr][kg];
    *(us8*)&WT[(size_t)(n0+nr)*Dn + k0+kg+8] = *(us8*)&Tt[nr][kg+8];
  } else {
    // E part: 4 rows per block, one row per 64-lane wave
    int row = (bx - (Bn*Tn + 256))*4 + (tid >> 6);
    int lane = tid & 63;
    const float* er = E + (size_t)row*Dn;
    unsigned short* ebr = Ebf + (size_t)row*Dn;
    float d1 = 0.f, d2 = 0.f;
    #pragma unroll
    for (int c = 0; c < 4; c++){
      int idx = c*64 + lane;
      float4 v = ((const float4*)er)[idx];
      float4 w1 = ((const float4*)Wn)[idx];
      float4 w2 = ((const float4*)(Wn + Dn))[idx];
      unsigned short o[4] = {f2bf(v.x), f2bf(v.y), f2bf(v.z), f2bf(v.w)};
      ((uint2*)ebr)[idx] = *(uint2*)o;
      d1 += v.x*w1.x + v.y*w1.y + v.z*w1.z + v.w*w1.w;
      d2 += v.x*w2.x + v.y*w2.y + v.z*w2.z + v.w*w2.w;
    }
    #pragma unroll
    for (int off = 32; off; off >>= 1){
      d1 += __shfl_down(d1, off, 64);
      d2 += __shfl_down(d2, off, 64);
    }
    if (lane == 0){ eW1[row] = d1; eW2[row] = d2; }
  }
}

// ------ qw_gemm: QW = Q @ Wq, 64x128 tiles, 480 blocks (~2/CU) -------------
__global__ __launch_bounds__(256) void qw_gemm(
    const unsigned short* __restrict__ Qbf,
    const unsigned short* __restrict__ WT,
    unsigned short* __restrict__ QWbf)
{
  int tid = threadIdx.x;
  // LDS: A 64x64 (8KB) + B 128x64 (16KB), double-buffered = 48KB.
  __shared__ __align__(16) unsigned short As0_[64*64],  Bs0_[128*64];
  __shared__ __align__(16) unsigned short As1_[64*64],  Bs1_[128*64];
  // 480 blocks = 60 m-tiles(64) x 8 n-tiles(128); XCD swizzle chunk=60.
  int bx = (blockIdx.x & 7)*60 + (blockIdx.x >> 3);
  int m0 = (bx >> 3)*64, n0 = (bx & 7)*128;
  int lane = tid & 63, wave = tid >> 6;
  int quad = lane >> 4, l16 = lane & 15;
  int wr = (wave >> 1)*32, wc = (wave & 1)*64;   // wave covers 32m x 64n
  f32x4 acc[2][4];
  #pragma unroll
  for (int mi=0;mi<2;mi++)
    #pragma unroll
    for (int ni=0;ni<4;ni++)
      #pragma unroll
      for (int r=0;r<4;r++) acc[mi][ni][r]=0.f;
  int lr = lane >> 3;                          // row within 8-row chunk
  int scol = ((lane & 7) ^ lr)*8;              // pre-swizzled source col
  const unsigned short* gA = Qbf + (size_t)(m0 + lr)*Dn + scol;
  const unsigned short* gB = WT  + (size_t)(n0 + lr)*Dn + scol;

  #define STAGE64(K, A_, B_) { \
    _Pragma("unroll") \
    for (int i = 0; i < 2; i++){ \
      int c = wave*2 + i; \
      gl16(gA + (size_t)c*8*Dn + (K), &A_[c*512]); \
    } \
    _Pragma("unroll") \
    for (int i = 0; i < 4; i++){ \
      int c = wave*4 + i; \
      gl16(gB + (size_t)c*8*Dn + (K), &B_[c*512]); \
    } }
  #define COMP64(A_, B_) { \
    _Pragma("unroll") \
    for (int ks = 0; ks < 2; ks++){ \
      bf16x8 af[2], bg[4]; \
      _Pragma("unroll") \
      for (int mi=0;mi<2;mi++){ \
        int mrow = wr + mi*16 + l16; \
        af[mi] = *(const bf16x8*)&A_[mrow*64 + ((ks*32 + quad*8) ^ ((mrow&7)*8))]; \
      } \
      _Pragma("unroll") \
      for (int ni=0;ni<4;ni++){ \
        int nrow = wc + ni*16 + l16; \
        bg[ni] = *(const bf16x8*)&B_[nrow*64 + ((ks*32 + quad*8) ^ ((nrow&7)*8))]; \
      } \
      _Pragma("unroll") \
      for (int mi=0;mi<2;mi++) \
        _Pragma("unroll") \
        for (int ni=0;ni<4;ni++) \
          acc[mi][ni] = __builtin_amdgcn_mfma_f32_16x16x32_bf16(af[mi], bg[ni], acc[mi][ni], 0, 0, 0); \
    } }

  STAGE64(0, As0_, Bs0_);
  __syncthreads();
  #pragma unroll 1
  for (int k0 = 0; k0 < Dn; k0 += 128){
    STAGE64(k0+64, As1_, Bs1_);        // k0+64 <= 960 < Dn always
    COMP64(As0_, Bs0_);
    __syncthreads();
    if (k0+128 < Dn) STAGE64(k0+128, As0_, Bs0_);
    COMP64(As1_, Bs1_);
    __syncthreads();
  }
  #undef STAGE64
  #undef COMP64

  #pragma unroll
  for (int mi=0;mi<2;mi++)
    #pragma unroll
    for (int ni=0;ni<4;ni++)
      #pragma unroll
      for (int r=0;r<4;r++){
        int m = m0 + wr + mi*16 + quad*4 + r;
        int n = n0 + wc + ni*16 + l16;
        QWbf[(size_t)m*Dn + n] = f2bf(acc[mi][ni][r]);
      }
}

// ------ gemm_g: G[b,t,s] = QW[b,t,:].Ebf[b,s,:], 60x32 tiles, fp32 out ------
__global__ __launch_bounds__(256) void gemm_g(
    const unsigned short* __restrict__ QWbf,
    const unsigned short* __restrict__ Ebf,
    float* __restrict__ G)
{
  __shared__ __align__(16) unsigned short As0_[64][LDK], As1_[64][LDK];
  __shared__ __align__(16) unsigned short Bs0_[32][LDK], Bs1_[32][LDK];
  int b = blockIdx.x, s0 = blockIdx.y*32;
  int tid = threadIdx.x, lane = tid & 63, wave = tid >> 6;
  int quad = lane >> 4, l16 = lane & 15;
  f32x4 acc[2];
  #pragma unroll
  for (int nt=0;nt<2;nt++)
    #pragma unroll
    for (int r=0;r<4;r++) acc[nt][r]=0.f;
  int sr = tid >> 2, sk = (tid & 3)*16;   // A staging: 64 rows x 64 k
  int brw = tid >> 3, bk = (tid & 7)*8;   // B staging: 32 rows x 64 k
  const unsigned short* aRow = QWbf + ((size_t)(b*Tn + sr))*Dn;
  const unsigned short* bRow = Ebf  + ((size_t)(b*Sn + s0 + brw))*Dn;

  #define LOADR(K, ra0, ra1, rb0) { \
    if (sr < Tn){ ra0 = *(const us8*)&aRow[(K)+sk]; ra1 = *(const us8*)&aRow[(K)+sk+8]; } \
    else { ra0 = (us8)0; ra1 = (us8)0; } \
    rb0 = *(const us8*)&bRow[(K)+bk]; }
  #define STORER(A_, B_, ra0, ra1, rb0) { \
    *(us8*)&A_[sr][sk]   = ra0; *(us8*)&A_[sr][sk+8] = ra1; \
    *(us8*)&B_[brw][bk]  = rb0; }
  #define COMP_G(A_, B_) { \
    _Pragma("unroll") \
    for (int kk = 0; kk < 64; kk += 32){ \
      bf16x8 a = *(const bf16x8*)&A_[wave*16 + l16][kk + quad*8]; \
      _Pragma("unroll") \
      for (int nt=0;nt<2;nt++){ \
        bf16x8 bb = *(const bf16x8*)&B_[nt*16 + l16][kk + quad*8]; \
        acc[nt] = __builtin_amdgcn_mfma_f32_16x16x32_bf16(a, bb, acc[nt], 0, 0, 0); \
      } \
    } }

  us8 pa0, pa1, pb0, qa0, qa1, qb0;
  LOADR(0, pa0, pa1, pb0);
  STORER(As0_, Bs0_, pa0, pa1, pb0);
  #pragma unroll 1
  for (int k0 = 0; k0 < Dn; k0 += 128){
    LOADR(k0+64, qa0, qa1, qb0);          // k0+64 <= 960 < Dn always
    __syncthreads();
    COMP_G(As0_, Bs0_);
    STORER(As1_, Bs1_, qa0, qa1, qb0);
    if (k0+128 < Dn) LOADR(k0+128, pa0, pa1, pb0);
    __syncthreads();
    COMP_G(As1_, Bs1_);
    if (k0+128 < Dn) STORER(As0_, Bs0_, pa0, pa1, pb0);
  }
  #undef LOADR
  #undef STORER
  #undef COMP_G

  #pragma unroll
  for (int nt=0;nt<2;nt++)
    #pragma unroll
    for (int r=0;r<4;r++){
      int t = wave*16 + quad*4 + r;
      if (t < Tn) G[((size_t)(b*Tn + t))*Sn + s0 + nt*16 + l16] = acc[nt][r];
    }
}

// ------ scan_s: one block per b; register-resident columns + unrolled scan --
__global__ __launch_bounds__(256) void scan_s(
    const float* __restrict__ G,
    const float* __restrict__ At,
    const float* __restrict__ rp,
    const float* __restrict__ ap,
    const float* __restrict__ eW1,
    const float* __restrict__ eW2,
    const float* __restrict__ bnp,
    unsigned short* __restrict__ Pbf)
{
  __shared__ float Rsh[Tn], lcs[Tn], rps[Tn], aps[Tn], invd[Tn];
  int b = blockIdx.x, tid = threadIdx.x;
  int lane = tid & 63, wave = tid >> 6;

  // 1) Burst-load this thread's At/G column into REGISTERS (static indices
  //    only -> VGPRs, rule #20). 120 independent coalesced loads in flight.
  float a_[Tn], g_[Tn];
  {
    const float* at_c = At + (size_t)b*Tn*Sn + tid;
    const float* g_c  = G  + (size_t)b*Tn*Sn + tid;
    #pragma unroll
    for (int i = 0; i < Tn; i++){
      a_[i] = at_c[(size_t)i*Sn];
      g_[i] = g_c[(size_t)i*Sn];
    }
  }

  // 2) R-dot (row-major float4 reads; overlaps the register burst):
  //    R[j] = At[b,j,:].eW2[b,:]
  {
    float4 e2v = ((const float4*)(eW2 + (size_t)b*Sn))[lane];
    const float* at_b = At + (size_t)b*Tn*Sn;
    #pragma unroll
    for (int w = 0; w < 15; w++){
      int j = wave + w*4;
      float4 a4 = ((const float4*)(at_b + (size_t)j*Sn))[lane];
      float v = a4.x*e2v.x + a4.y*e2v.y + a4.z*e2v.z + a4.w*e2v.w;
      #pragma unroll
      for (int off = 32; off; off >>= 1) v += __shfl_down(v, off, 64);
      if (lane == 0) Rsh[j] = v;
    }
  }
  if (tid < Tn){
    rps[tid] = rp[b*Tn + tid];
    aps[tid] = ap[b*Tn + tid];
  }
  __syncthreads();

  // 3) lc + 1/den (den data-independent, shared with the scan)
  if (tid < Tn){
    int i = tid;
    int j0 = (i - HISTn + 1 > 0) ? i - HISTn + 1 : 0;
    float num = 0.f, den = 0.f, wj = 1.f;
    #pragma unroll 1
    for (int j = 0; j <= i; j++){
      wj *= K05;
      if (j >= j0){ num += wj * Rsh[j]; den += wj; }
    }
    float inv = __builtin_amdgcn_rcpf(den);
    lcs[i] = num * inv;
    invd[i] = inv;
  }
  __syncthreads();

  // 4) Scan: fully unrolled, pure-register (body ~30 instrs x 60 ~= 8KB,
  //    L1i-resident with the 4-instr sigmoid).
  {
    int s = tid;
    float M = (s < 50) ? (1.0f - (s+1)/50.0f) : 0.0f;
    float A = M;
    float bnv = bnp[0];
    float e1 = eW1[b*Sn + s];
    unsigned short* P_b = Pbf + (size_t)b*Tn*Sn + s;
    float num_a = 0.f, num_q = 0.f, wi = 1.f;
    #pragma unroll
    for (int i = 0; i < Tn; i++){
      wi *= K05;
      num_a += wi * a_[i];
      num_q += wi * g_[i];
      if (i >= HISTn){
        float wo = wi * EINV;
        num_a -= wo * a_[i-HISTn];
        num_q -= wo * g_[i-HISTn];
      }
      float inv = invd[i];
      float aw = num_a * inv;
      float qd = num_q * inv;
      P_b[(size_t)i*Sn] = f2bf(a_[i] * M);   // sel uses mem at step ENTRY
      float sim = sigmoidf_(M * qd);
      float nxt = sigmoidf_(e1 + lcs[i] + bnv);
      M = M * (1.0f - rps[i] * aw * sim);
      float g = (1.0f - A) * aps[i] * nxt;
      M += g; A += g;
    }
  }
}

// ------ gemm_sels: out[b] = P[b](TxS) @ Ebf[b](SxD), single-buffer + T14 ----
__global__ __launch_bounds__(256) void gemm_sels(
    const unsigned short* __restrict__ Pbf,
    const unsigned short* __restrict__ Ebf,
    float* __restrict__ out)
{
  __shared__ __align__(16) unsigned short As_[64][LDK], Bs_[64][LDK];
  int b = blockIdx.x, n0 = blockIdx.y*64;   // n over D
  int tid = threadIdx.x, lane = tid & 63, wave = tid >> 6;
  int quad = lane >> 4, l16 = lane & 15;
  f32x4 acc[4];
  #pragma unroll
  for (int nt=0;nt<4;nt++)
    #pragma unroll
    for (int r=0;r<4;r++) acc[nt][r]=0.f;
  int sr = tid >> 2, sk = (tid & 3)*16;

  #define SLOAD(K) { \
    if (sr < Tn){ \
      const unsigned short* pp = &Pbf[((size_t)(b*Tn + sr))*Sn + (K)+sk]; \
      pa0 = *(const us8*)pp; pa1 = *(const us8*)(pp+8); \
    } else { pa0 = (us8)0; pa1 = (us8)0; } \
    const unsigned short* ep = &Ebf[((size_t)(b*Sn + (K) + sr))*Dn + n0 + sk]; \
    pe0 = *(const us8*)ep; pe1 = *(const us8*)(ep + 8); }
  #define SSTORE() { \
    *(us8*)&As_[sr][sk]   = pa0; *(us8*)&As_[sr][sk+8] = pa1; \
    _Pragma("unroll") \
    for (int j=0;j<8;j++){ \
      Bs_[sk+j][sr]   = pe0[j]; \
      Bs_[sk+8+j][sr] = pe1[j]; } }
  #define COMP_S() { \
    _Pragma("unroll") \
    for (int kk = 0; kk < 64; kk += 32){ \
      bf16x8 a = *(const bf16x8*)&As_[wave*16 + l16][kk + quad*8]; \
      _Pragma("unroll") \
      for (int nt=0;nt<4;nt++){ \
        bf16x8 bb = *(const bf16x8*)&Bs_[nt*16 + l16][kk + quad*8]; \
        acc[nt] = __builtin_amdgcn_mfma_f32_16x16x32_bf16(a, bb, acc[nt], 0, 0, 0); \
      } \
    } }

  us8 pa0, pa1, pe0, pe1;
  SLOAD(0);
  SSTORE();
  #pragma unroll
  for (int k0 = 0; k0 < Sn; k0 += 64){
    __syncthreads();                       // stores visible
    if (k0+64 < Sn) SLOAD(k0+64);          // issue next loads early (T14)
    COMP_S();
    __syncthreads();                       // reads done before overwrite
    if (k0+64 < Sn) SSTORE();
  }
  #undef SLOAD
  #undef SSTORE
  #undef COMP_S

  #pragma unroll
  for (int nt=0;nt<4;nt++)
    #pragma unroll
    for (int r=0;r<4;r++){
      int t = wave*16 + quad*4 + r;
      int d = n0 + nt*16 + l16;
      if (t < Tn) out[((size_t)(b*Tn + t))*Dn + d] = acc[nt][r];
    }
}

extern "C" void kernel_launch(void* const* d_in, const int* in_sizes, int n_in,
                              void* d_out, int out_size, void* d_ws, size_t ws_size,
                              hipStream_t stream)
{
  const float* E  = (const float*)d_in[0];
  const float* Q  = (const float*)d_in[1];
  const float* At = (const float*)d_in[2];
  const float* Wr = (const float*)d_in[3];
  const float* br = (const float*)d_in[4];
  const float* Wa = (const float*)d_in[5];
  const float* ba = (const float*)d_in[6];
  const float* Wq = (const float*)d_in[7];
  const float* Wn = (const float*)d_in[8];
  const float* bnp= (const float*)d_in[9];

  char* ws = (char*)d_ws;
  float* rp  = (float*)ws; ws += (size_t)Bn*Tn*4;
  float* ap  = (float*)ws; ws += (size_t)Bn*Tn*4;
  float* eW1 = (float*)ws; ws += (size_t)Bn*Sn*4;
  float* eW2 = (float*)ws; ws += (size_t)Bn*Sn*4;
  unsigned short* Qbf  = (unsigned short*)ws; ws += (size_t)Bn*Tn*Dn*2;  // 7.86 MB
  unsigned short* WT   = (unsigned short*)ws; ws += (size_t)Dn*Dn*2;     // 2.1 MB
  unsigned short* QWbf = (unsigned short*)ws; ws += (size_t)Bn*Tn*Dn*2;  // 7.86 MB
  unsigned short* Ebf  = (unsigned short*)ws; ws += (size_t)Bn*Sn*Dn*2;  // 33.6 MB
  float* G = (float*)ws; ws += (size_t)Bn*Tn*Sn*4;                       // 3.93 MB
  unsigned short* Pbf = (unsigned short*)ws; ws += (size_t)Bn*Tn*Sn*2;   // 1.97 MB

  convAll<<<Bn*Tn + 256 + Bn*Sn/4, 256, 0, stream>>>(
      Q, Wr, br, Wa, ba, Wq, E, Wn, rp, ap, Qbf, WT, Ebf, eW1, eW2);
  qw_gemm<<<480, 256, 0, stream>>>(Qbf, WT, QWbf);
  gemm_g<<<dim3(Bn, Sn/32), 256, 0, stream>>>(QWbf, Ebf, G);
  scan_s<<<Bn, 256, 0, stream>>>(G, At, rp, ap, eW1, eW2, bnp, Pbf);
  gemm_sels<<<dim3(Bn, Dn/64), 256, 0, stream>>>(Pbf, Ebf, (float*)d_out);
}